// Round 1
// baseline (49446.240 us; speedup 1.0000x reference)
//
#include <hip/hip_runtime.h>
#include <hip/hip_bf16.h>

#define B_ 64
#define S_ 256
#define IN_ 512
#define H_ 1024
#define O_ 512
#define K_ 4
#define T_ (S_*K_)      // 1024
#define H3_ (3*H_)      // 3072

#define NC_ 4           // clusters
#define CPC_ 64         // WGs (CUs) per cluster
#define RPC_ 16         // batch rows per cluster

typedef __attribute__((ext_vector_type(8))) short bf16x8;
typedef __attribute__((ext_vector_type(4))) float f32x4;
typedef unsigned short ushort_t;
typedef unsigned int uint_t;
typedef unsigned long long ull_t;

__device__ __forceinline__ ushort_t f2b(float f) {
    union { float f; unsigned u; } v; v.f = f;
    unsigned r = v.u + 0x7FFFu + ((v.u >> 16) & 1u);
    return (ushort_t)(r >> 16);
}
__device__ __forceinline__ float b2f(ushort_t h) {
    union { unsigned u; float f; } v; v.u = ((unsigned)h) << 16; return v.f;
}

// ---------------------------------------------------------------------------
// gi = x @ W_ih^T + b_ih   (bf16 output), M=16384, N=3072, K=512
// ---------------------------------------------------------------------------
__global__ __launch_bounds__(256) void gi_gemm(const float* __restrict__ x,
                                               const float* __restrict__ Wih,
                                               const float* __restrict__ bih,
                                               ushort_t* __restrict__ gi) {
    const int NB = H3_ / 64;                 // 48
    const int nb = blockIdx.x % NB;
    const int mb = blockIdx.x / NB;
    const int tid = threadIdx.x, lane = tid & 63, w = tid >> 6;
    const int wm = w >> 1, wn = w & 1;
    __shared__ ushort_t Al[64][40];
    __shared__ ushort_t Bl[64][40];
    f32x4 acc[2][2] = {};
    const int lrow = tid >> 2, lk = (tid & 3) * 8;
    for (int k0 = 0; k0 < IN_; k0 += 32) {
        const float* xs = &x[(size_t)(mb*64 + lrow)*IN_ + k0 + lk];
        const float* ws = &Wih[(size_t)(nb*64 + lrow)*IN_ + k0 + lk];
        #pragma unroll
        for (int i = 0; i < 8; ++i) Al[lrow][lk+i] = f2b(xs[i]);
        #pragma unroll
        for (int i = 0; i < 8; ++i) Bl[lrow][lk+i] = f2b(ws[i]);
        __syncthreads();
        const int fr = lane & 15, fk = (lane >> 4) * 8;
        #pragma unroll
        for (int mt = 0; mt < 2; ++mt) {
            bf16x8 a = *(const bf16x8*)&Al[wm*32 + mt*16 + fr][fk];
            #pragma unroll
            for (int nt = 0; nt < 2; ++nt) {
                bf16x8 b = *(const bf16x8*)&Bl[wn*32 + nt*16 + fr][fk];
                acc[mt][nt] = __builtin_amdgcn_mfma_f32_16x16x32_bf16(a, b, acc[mt][nt], 0, 0, 0);
            }
        }
        __syncthreads();
    }
    const int fr = lane & 15, fm = (lane >> 4) * 4;
    #pragma unroll
    for (int mt = 0; mt < 2; ++mt)
    #pragma unroll
    for (int nt = 0; nt < 2; ++nt)
    #pragma unroll
    for (int i = 0; i < 4; ++i) {
        int gm = mb*64 + wm*32 + mt*16 + fm + i;
        int gn = nb*64 + wn*32 + nt*16 + fr;
        gi[(size_t)gm*H3_ + gn] = f2b(acc[mt][nt][i] + bih[gn]);
    }
}

// ---------------------------------------------------------------------------
// Persistent recurrent kernel. 256 WGs = 4 clusters x 64 WGs. One WG per CU.
// Each WG owns 16 h-columns (48 gate rows of W_hh resident in LDS) and the
// cluster's 16 batch rows. Cluster-local atomic barrier per tick.
// ---------------------------------------------------------------------------
__global__ __launch_bounds__(256) void rec_kernel(const ushort_t* __restrict__ gi,
                                                  const float* __restrict__ Whh,
                                                  const float* __restrict__ bhh,
                                                  ushort_t* __restrict__ hstates,
                                                  int* __restrict__ bars) {
    const int wg = blockIdx.x;
    const int c  = wg >> 6;        // cluster
    const int cu = wg & 63;        // position within cluster
    const int tid = threadIdx.x, lane = tid & 63, w = tid >> 6;
    const int r_el = tid >> 4, jl = tid & 15;   // elementwise mapping
    const int colbase = cu << 4;                // 16 h-cols per WG
    const int b0 = c * RPC_;                    // batch row base

    __shared__ ushort_t wlds[3][16][1032];      // 99072 B   W_hh slice (bf16)
    __shared__ ushort_t hlds[16][1032];         // 33024 B   cluster h (bf16)
    __shared__ float red[4][16][48];            // 12288 B   per-wave partials

    // Load W_hh slice once: gate g, local col j -> row g*1024 + colbase + j
    for (int idx = tid; idx < 3*16*1024; idx += 256) {
        int g = idx >> 14, rem = idx & 16383;
        int j = rem >> 10, k = rem & 1023;
        wlds[g][j][k] = f2b(Whh[(size_t)(g*H_ + colbase + j)*H_ + k]);
    }
    const float bh_r = bhh[colbase + jl];
    const float bh_z = bhh[H_ + colbase + jl];
    const float bh_n = bhh[2*H_ + colbase + jl];

    float h_prev = 0.f;
    float gir = 0.f, giz = 0.f, gin = 0.f;
    int s_cur = -1;

    int* bar = &bars[c << 5];   // 128B-separated cluster counters

    for (int t = 0; t < T_; ++t) {
        // refresh gi at timestep boundary (every K_ ticks)
        int s = t >> 2;
        if (s != s_cur) {
            s_cur = s;
            size_t row = ((size_t)(b0 + r_el)*S_ + s)*H3_ + colbase + jl;
            gir = b2f(gi[row]);
            giz = b2f(gi[row + H_]);
            gin = b2f(gi[row + 2*H_]);
        }
        // stage cluster h into LDS (agent-scope loads bypass L1/L2)
        if (t == 0) {
            for (int idx = tid; idx < 16*516; idx += 256) ((uint_t*)hlds)[idx] = 0u;
        } else {
            const ull_t* hsrc = (const ull_t*)hstates;  // 256 ull per h-row
            for (int idx = tid; idx < 16*256; idx += 256) {
                int rr = idx >> 8, kq = idx & 255;
                ull_t v = __hip_atomic_load(&hsrc[((size_t)(b0+rr)*T_ + (t-1))*256 + kq],
                                            __ATOMIC_RELAXED, __HIP_MEMORY_SCOPE_AGENT);
                *(ull_t*)&hlds[rr][kq << 2] = v;
            }
        }
        __syncthreads();

        // MFMA: wave w covers k in [w*256, w*256+256); 3 gates, M=16 tile
        f32x4 acc0 = {}, acc1 = {}, acc2 = {};
        {
            const int fr = lane & 15, koff = (lane >> 4) << 3;
            #pragma unroll
            for (int ks = 0; ks < 8; ++ks) {
                int k = (w << 8) + (ks << 5) + koff;
                bf16x8 a  = *(const bf16x8*)&hlds[fr][k];
                bf16x8 b0v = *(const bf16x8*)&wlds[0][fr][k];
                bf16x8 b1v = *(const bf16x8*)&wlds[1][fr][k];
                bf16x8 b2v = *(const bf16x8*)&wlds[2][fr][k];
                acc0 = __builtin_amdgcn_mfma_f32_16x16x32_bf16(a, b0v, acc0, 0, 0, 0);
                acc1 = __builtin_amdgcn_mfma_f32_16x16x32_bf16(a, b1v, acc1, 0, 0, 0);
                acc2 = __builtin_amdgcn_mfma_f32_16x16x32_bf16(a, b2v, acc2, 0, 0, 0);
            }
        }
        {
            const int n = lane & 15, m = (lane >> 4) << 2;
            #pragma unroll
            for (int i = 0; i < 4; ++i) {
                red[w][m+i][n]      = acc0[i];
                red[w][m+i][16+n]   = acc1[i];
                red[w][m+i][32+n]   = acc2[i];
            }
        }
        __syncthreads();

        // elementwise GRU update: thread (r_el, jl)
        float ghr = red[0][r_el][jl]    + red[1][r_el][jl]    + red[2][r_el][jl]    + red[3][r_el][jl];
        float ghz = red[0][r_el][16+jl] + red[1][r_el][16+jl] + red[2][r_el][16+jl] + red[3][r_el][16+jl];
        float ghn = red[0][r_el][32+jl] + red[1][r_el][32+jl] + red[2][r_el][32+jl] + red[3][r_el][32+jl];
        float rr_ = 1.f / (1.f + __expf(-(gir + ghr + bh_r)));
        float zz  = 1.f / (1.f + __expf(-(giz + ghz + bh_z)));
        float nn  = tanhf(gin + rr_ * (ghn + bh_n));
        float hn  = (1.f - zz) * nn + zz * h_prev;
        h_prev = hn;
        __hip_atomic_store(&hstates[((size_t)(b0 + r_el)*T_ + t)*H_ + colbase + jl],
                           f2b(hn), __ATOMIC_RELAXED, __HIP_MEMORY_SCOPE_AGENT);

        __threadfence();
        __syncthreads();
        if (tid == 0) {
            __hip_atomic_fetch_add(bar, 1, __ATOMIC_ACQ_REL, __HIP_MEMORY_SCOPE_AGENT);
            const int target = (t + 1) * CPC_;
            while (__hip_atomic_load(bar, __ATOMIC_ACQUIRE, __HIP_MEMORY_SCOPE_AGENT) < target)
                __builtin_amdgcn_s_sleep(2);
        }
        __syncthreads();
        __threadfence();
    }
}

// ---------------------------------------------------------------------------
// logits = (hstates @ W_fc^T + b_fc) * seq_mask  (f32 out, straight to d_out)
// M = 65536 (b*T + t), N = 512, K = 1024
// ---------------------------------------------------------------------------
__global__ __launch_bounds__(256) void logits_gemm(const ushort_t* __restrict__ hstates,
                                                   const float* __restrict__ Wfc,
                                                   const float* __restrict__ bfc,
                                                   const float* __restrict__ sm,
                                                   float* __restrict__ out) {
    const int NB = O_ / 64;                  // 8
    const int nb = blockIdx.x % NB;
    const int mb = blockIdx.x / NB;
    const int tid = threadIdx.x, lane = tid & 63, w = tid >> 6;
    const int wm = w >> 1, wn = w & 1;
    __shared__ ushort_t Al[64][40];
    __shared__ ushort_t Bl[64][40];
    f32x4 acc[2][2] = {};
    const int lrow = tid >> 2, lk = (tid & 3) * 8;
    for (int k0 = 0; k0 < H_; k0 += 32) {
        uint4 va = *(const uint4*)&hstates[(size_t)(mb*64 + lrow)*H_ + k0 + lk];
        *(uint4*)&Al[lrow][lk] = va;
        const float* ws = &Wfc[(size_t)(nb*64 + lrow)*H_ + k0 + lk];
        #pragma unroll
        for (int i = 0; i < 8; ++i) Bl[lrow][lk+i] = f2b(ws[i]);
        __syncthreads();
        const int fr = lane & 15, fk = (lane >> 4) * 8;
        #pragma unroll
        for (int mt = 0; mt < 2; ++mt) {
            bf16x8 a = *(const bf16x8*)&Al[wm*32 + mt*16 + fr][fk];
            #pragma unroll
            for (int nt = 0; nt < 2; ++nt) {
                bf16x8 b = *(const bf16x8*)&Bl[wn*32 + nt*16 + fr][fk];
                acc[mt][nt] = __builtin_amdgcn_mfma_f32_16x16x32_bf16(a, b, acc[mt][nt], 0, 0, 0);
            }
        }
        __syncthreads();
    }
    const int fr = lane & 15, fm = (lane >> 4) * 4;
    #pragma unroll
    for (int mt = 0; mt < 2; ++mt)
    #pragma unroll
    for (int nt = 0; nt < 2; ++nt)
    #pragma unroll
    for (int i = 0; i < 4; ++i) {
        int R  = mb*64 + wm*32 + mt*16 + fm + i;     // b*T + t
        int gn = nb*64 + wn*32 + nt*16 + fr;
        int b  = R >> 10, t = R & (T_ - 1);
        float mval = sm[b*S_ + (t >> 2)];
        out[(size_t)R*O_ + gn] = (acc[mt][nt][i] + bfc[gn]) * mval;
    }
}

// ---------------------------------------------------------------------------
// y_res (as f32) and ok (as f32 0/1)
// ---------------------------------------------------------------------------
__global__ void tail_kernel(const int* __restrict__ y, const float* __restrict__ sm,
                            float* __restrict__ yout, float* __restrict__ okout) {
    int i = blockIdx.x * 256 + threadIdx.x;
    if (i < B_ * T_) {
        int b = i >> 10, t = i & 1023, s = t >> 2;
        yout[i]  = (float)y[b*S_ + s];
        okout[i] = (sm[b*S_ + s] != 0.0f) ? 1.0f : 0.0f;
    }
}

// ---------------------------------------------------------------------------
extern "C" void kernel_launch(void* const* d_in, const int* in_sizes, int n_in,
                              void* d_out, int out_size, void* d_ws, size_t ws_size,
                              hipStream_t stream) {
    (void)in_sizes; (void)n_in; (void)out_size; (void)ws_size;
    const float* x   = (const float*)d_in[0];
    const int*   y   = (const int*)d_in[1];
    const float* sm  = (const float*)d_in[2];
    const float* Wih = (const float*)d_in[4];
    const float* Whh = (const float*)d_in[5];
    const float* bih = (const float*)d_in[6];
    const float* bhh = (const float*)d_in[7];
    const float* Wfc = (const float*)d_in[8];
    const float* bfc = (const float*)d_in[9];

    char* ws = (char*)d_ws;
    ushort_t* gi      = (ushort_t*)ws;                                  // 100,663,296 B
    ushort_t* hstates = (ushort_t*)(ws + 100663296);                    // 134,217,728 B
    int*      bars    = (int*)(ws + 100663296 + 134217728);             // 4 KB

    hipMemsetAsync(bars, 0, 4096, stream);

    hipLaunchKernelGGL(gi_gemm, dim3((B_*S_/64)*(H3_/64)), dim3(256), 0, stream,
                       x, Wih, bih, gi);

    void* args[] = { (void*)&gi, (void*)&Whh, (void*)&bhh, (void*)&hstates, (void*)&bars };
    hipLaunchCooperativeKernel((void*)rec_kernel, dim3(NC_*CPC_), dim3(256), args, 0, stream);

    hipLaunchKernelGGL(logits_gemm, dim3((B_*T_/64)*(O_/64)), dim3(256), 0, stream,
                       hstates, Wfc, bfc, sm, (float*)d_out);

    float* yout  = (float*)d_out + (size_t)B_*T_*O_;
    float* okout = yout + (size_t)B_*T_;
    hipLaunchKernelGGL(tail_kernel, dim3(B_*T_/256), dim3(256), 0, stream,
                       y, sm, yout, okout);
}

// Round 2
// 7942.355 us; speedup vs baseline: 6.2256x; 6.2256x over previous
//
#include <hip/hip_runtime.h>
#include <hip/hip_bf16.h>

#define B_ 64
#define S_ 256
#define IN_ 512
#define H_ 1024
#define O_ 512
#define K_ 4
#define T_ (S_*K_)      // 1024
#define H3_ (3*H_)      // 3072

#define NC_ 4           // clusters
#define CPC_ 64         // WGs (CUs) per cluster
#define RPC_ 16         // batch rows per cluster

typedef __attribute__((ext_vector_type(8))) short bf16x8;
typedef __attribute__((ext_vector_type(4))) float f32x4;
typedef unsigned short ushort_t;
typedef unsigned int uint_t;
typedef unsigned long long ull_t;

__device__ __forceinline__ ushort_t f2b(float f) {
    union { float f; unsigned u; } v; v.f = f;
    unsigned r = v.u + 0x7FFFu + ((v.u >> 16) & 1u);
    return (ushort_t)(r >> 16);
}
__device__ __forceinline__ float b2f(ushort_t h) {
    union { unsigned u; float f; } v; v.u = ((unsigned)h) << 16; return v.f;
}

// ---------------------------------------------------------------------------
// gi = x @ W_ih^T + b_ih   (bf16 output), M=16384, N=3072, K=512
// ---------------------------------------------------------------------------
__global__ __launch_bounds__(256) void gi_gemm(const float* __restrict__ x,
                                               const float* __restrict__ Wih,
                                               const float* __restrict__ bih,
                                               ushort_t* __restrict__ gi) {
    const int NB = H3_ / 64;                 // 48
    const int nb = blockIdx.x % NB;
    const int mb = blockIdx.x / NB;
    const int tid = threadIdx.x, lane = tid & 63, w = tid >> 6;
    const int wm = w >> 1, wn = w & 1;
    __shared__ ushort_t Al[64][40];
    __shared__ ushort_t Bl[64][40];
    f32x4 acc[2][2] = {};
    const int lrow = tid >> 2, lk = (tid & 3) * 8;
    for (int k0 = 0; k0 < IN_; k0 += 32) {
        const float* xs = &x[(size_t)(mb*64 + lrow)*IN_ + k0 + lk];
        const float* ws = &Wih[(size_t)(nb*64 + lrow)*IN_ + k0 + lk];
        #pragma unroll
        for (int i = 0; i < 8; ++i) Al[lrow][lk+i] = f2b(xs[i]);
        #pragma unroll
        for (int i = 0; i < 8; ++i) Bl[lrow][lk+i] = f2b(ws[i]);
        __syncthreads();
        const int fr = lane & 15, fk = (lane >> 4) * 8;
        #pragma unroll
        for (int mt = 0; mt < 2; ++mt) {
            bf16x8 a = *(const bf16x8*)&Al[wm*32 + mt*16 + fr][fk];
            #pragma unroll
            for (int nt = 0; nt < 2; ++nt) {
                bf16x8 b = *(const bf16x8*)&Bl[wn*32 + nt*16 + fr][fk];
                acc[mt][nt] = __builtin_amdgcn_mfma_f32_16x16x32_bf16(a, b, acc[mt][nt], 0, 0, 0);
            }
        }
        __syncthreads();
    }
    const int fr = lane & 15, fm = (lane >> 4) * 4;
    #pragma unroll
    for (int mt = 0; mt < 2; ++mt)
    #pragma unroll
    for (int nt = 0; nt < 2; ++nt)
    #pragma unroll
    for (int i = 0; i < 4; ++i) {
        int gm = mb*64 + wm*32 + mt*16 + fm + i;
        int gn = nb*64 + wn*32 + nt*16 + fr;
        gi[(size_t)gm*H3_ + gn] = f2b(acc[mt][nt][i] + bih[gn]);
    }
}

// ---------------------------------------------------------------------------
// Persistent recurrent kernel. 256 WGs = 4 clusters x 64 WGs. One WG per CU.
// Sync per tick: per-WG monotonic flag (RELAXED agent store after barrier
// drain), wave-0 polls all 64 cluster flags with RELAXED loads (no L2 inv).
// ---------------------------------------------------------------------------
__global__ __launch_bounds__(256) void rec_kernel(const ushort_t* __restrict__ gi,
                                                  const float* __restrict__ Whh,
                                                  const float* __restrict__ bhh,
                                                  ushort_t* __restrict__ hstates,
                                                  int* __restrict__ flags) {
    const int wg = blockIdx.x;
    const int c  = wg >> 6;        // cluster
    const int cu = wg & 63;        // position within cluster
    const int tid = threadIdx.x, lane = tid & 63, w = tid >> 6;
    const int r_el = tid >> 4, jl = tid & 15;   // elementwise mapping
    const int colbase = cu << 4;                // 16 h-cols per WG
    const int b0 = c * RPC_;                    // batch row base

    __shared__ ushort_t wlds[3][16][1032];      // 99072 B   W_hh slice (bf16)
    __shared__ ushort_t hlds[16][1032];         // 33024 B   cluster h (bf16)
    __shared__ float red[4][16][48];            // 12288 B   per-wave partials

    // Load W_hh slice once: gate g, local col j -> row g*1024 + colbase + j
    for (int idx = tid; idx < 3*16*1024; idx += 256) {
        int g = idx >> 14, rem = idx & 16383;
        int j = rem >> 10, k = rem & 1023;
        wlds[g][j][k] = f2b(Whh[(size_t)(g*H_ + colbase + j)*H_ + k]);
    }
    const float bh_r = bhh[colbase + jl];
    const float bh_z = bhh[H_ + colbase + jl];
    const float bh_n = bhh[2*H_ + colbase + jl];

    // zero h tile (t=0 reads zeros)
    for (int idx = tid; idx < 16*516; idx += 256) ((uint_t*)hlds)[idx] = 0u;

    float h_prev = 0.f;
    float gir = 0.f, giz = 0.f, gin = 0.f;
    int s_cur = -1;

    int* cflags = &flags[c << 6];   // 64 ints per cluster

    for (int t = 0; t < T_; ++t) {
        // refresh gi at timestep boundary (every K_ ticks)
        int s = t >> 2;
        if (s != s_cur) {
            s_cur = s;
            size_t row = ((size_t)(b0 + r_el)*S_ + s)*H3_ + colbase + jl;
            gir = b2f(gi[row]);
            giz = b2f(gi[row + H_]);
            gin = b2f(gi[row + 2*H_]);
        }
        // stage cluster h(t-1) into LDS (bypass loads served at MALL)
        if (t > 0) {
            const ull_t* hsrc = (const ull_t*)hstates;  // 256 ull per h-row
            #pragma unroll 4
            for (int idx = tid; idx < 16*256; idx += 256) {
                int rr = idx >> 8, kq = idx & 255;
                ull_t v = __hip_atomic_load(&hsrc[((size_t)(b0+rr)*T_ + (t-1))*256 + kq],
                                            __ATOMIC_RELAXED, __HIP_MEMORY_SCOPE_AGENT);
                *(ull_t*)&hlds[rr][kq << 2] = v;
            }
        }
        __syncthreads();

        // MFMA: wave w covers k in [w*256, w*256+256); 3 gates, M=16 tile
        f32x4 acc0 = {}, acc1 = {}, acc2 = {};
        {
            const int fr = lane & 15, koff = (lane >> 4) << 3;
            #pragma unroll
            for (int ks = 0; ks < 8; ++ks) {
                int k = (w << 8) + (ks << 5) + koff;
                bf16x8 a  = *(const bf16x8*)&hlds[fr][k];
                bf16x8 b0v = *(const bf16x8*)&wlds[0][fr][k];
                bf16x8 b1v = *(const bf16x8*)&wlds[1][fr][k];
                bf16x8 b2v = *(const bf16x8*)&wlds[2][fr][k];
                acc0 = __builtin_amdgcn_mfma_f32_16x16x32_bf16(a, b0v, acc0, 0, 0, 0);
                acc1 = __builtin_amdgcn_mfma_f32_16x16x32_bf16(a, b1v, acc1, 0, 0, 0);
                acc2 = __builtin_amdgcn_mfma_f32_16x16x32_bf16(a, b2v, acc2, 0, 0, 0);
            }
        }
        {
            const int n = lane & 15, m = (lane >> 4) << 2;
            #pragma unroll
            for (int i = 0; i < 4; ++i) {
                red[w][m+i][n]      = acc0[i];
                red[w][m+i][16+n]   = acc1[i];
                red[w][m+i][32+n]   = acc2[i];
            }
        }
        __syncthreads();

        // elementwise GRU update: thread (r_el, jl)
        float ghr = red[0][r_el][jl]    + red[1][r_el][jl]    + red[2][r_el][jl]    + red[3][r_el][jl];
        float ghz = red[0][r_el][16+jl] + red[1][r_el][16+jl] + red[2][r_el][16+jl] + red[3][r_el][16+jl];
        float ghn = red[0][r_el][32+jl] + red[1][r_el][32+jl] + red[2][r_el][32+jl] + red[3][r_el][32+jl];
        float rr_ = 1.f / (1.f + __expf(-(gir + ghr + bh_r)));
        float zz  = 1.f / (1.f + __expf(-(giz + ghz + bh_z)));
        float nn  = tanhf(gin + rr_ * (ghn + bh_n));
        float hn  = (1.f - zz) * nn + zz * h_prev;
        h_prev = hn;
        __hip_atomic_store(&hstates[((size_t)(b0 + r_el)*T_ + t)*H_ + colbase + jl],
                           f2b(hn), __ATOMIC_RELAXED, __HIP_MEMORY_SCOPE_AGENT);

        // barrier drains vmcnt(0) in every wave -> all bypass stores acked at
        // the coherence point before any wave proceeds.
        __syncthreads();

        if (w == 0) {
            if (lane == 0)
                __hip_atomic_store(&cflags[cu], t + 1, __ATOMIC_RELAXED,
                                   __HIP_MEMORY_SCOPE_AGENT);
            // 64 lanes poll the cluster's 64 flags: one 256B load per iter,
            // RELAXED (no buffer_inv spam).
            for (;;) {
                int v = __hip_atomic_load(&cflags[lane], __ATOMIC_RELAXED,
                                          __HIP_MEMORY_SCOPE_AGENT);
                if (__all(v >= t + 1)) break;
                __builtin_amdgcn_s_sleep(2);
            }
        }
        __syncthreads();
    }
}

// ---------------------------------------------------------------------------
// logits = (hstates @ W_fc^T + b_fc) * seq_mask  (f32 out, straight to d_out)
// M = 65536 (b*T + t), N = 512, K = 1024
// ---------------------------------------------------------------------------
__global__ __launch_bounds__(256) void logits_gemm(const ushort_t* __restrict__ hstates,
                                                   const float* __restrict__ Wfc,
                                                   const float* __restrict__ bfc,
                                                   const float* __restrict__ sm,
                                                   float* __restrict__ out) {
    const int NB = O_ / 64;                  // 8
    const int nb = blockIdx.x % NB;
    const int mb = blockIdx.x / NB;
    const int tid = threadIdx.x, lane = tid & 63, w = tid >> 6;
    const int wm = w >> 1, wn = w & 1;
    __shared__ ushort_t Al[64][40];
    __shared__ ushort_t Bl[64][40];
    f32x4 acc[2][2] = {};
    const int lrow = tid >> 2, lk = (tid & 3) * 8;
    for (int k0 = 0; k0 < H_; k0 += 32) {
        uint4 va = *(const uint4*)&hstates[(size_t)(mb*64 + lrow)*H_ + k0 + lk];
        *(uint4*)&Al[lrow][lk] = va;
        const float* ws = &Wfc[(size_t)(nb*64 + lrow)*H_ + k0 + lk];
        #pragma unroll
        for (int i = 0; i < 8; ++i) Bl[lrow][lk+i] = f2b(ws[i]);
        __syncthreads();
        const int fr = lane & 15, fk = (lane >> 4) * 8;
        #pragma unroll
        for (int mt = 0; mt < 2; ++mt) {
            bf16x8 a = *(const bf16x8*)&Al[wm*32 + mt*16 + fr][fk];
            #pragma unroll
            for (int nt = 0; nt < 2; ++nt) {
                bf16x8 b = *(const bf16x8*)&Bl[wn*32 + nt*16 + fr][fk];
                acc[mt][nt] = __builtin_amdgcn_mfma_f32_16x16x32_bf16(a, b, acc[mt][nt], 0, 0, 0);
            }
        }
        __syncthreads();
    }
    const int fr = lane & 15, fm = (lane >> 4) * 4;
    #pragma unroll
    for (int mt = 0; mt < 2; ++mt)
    #pragma unroll
    for (int nt = 0; nt < 2; ++nt)
    #pragma unroll
    for (int i = 0; i < 4; ++i) {
        int R  = mb*64 + wm*32 + mt*16 + fm + i;     // b*T + t
        int gn = nb*64 + wn*32 + nt*16 + fr;
        int b  = R >> 10, t = R & (T_ - 1);
        float mval = sm[b*S_ + (t >> 2)];
        out[(size_t)R*O_ + gn] = (acc[mt][nt][i] + bfc[gn]) * mval;
    }
}

// ---------------------------------------------------------------------------
// y_res (as f32) and ok (as f32 0/1)
// ---------------------------------------------------------------------------
__global__ void tail_kernel(const int* __restrict__ y, const float* __restrict__ sm,
                            float* __restrict__ yout, float* __restrict__ okout) {
    int i = blockIdx.x * 256 + threadIdx.x;
    if (i < B_ * T_) {
        int b = i >> 10, t = i & 1023, s = t >> 2;
        yout[i]  = (float)y[b*S_ + s];
        okout[i] = (sm[b*S_ + s] != 0.0f) ? 1.0f : 0.0f;
    }
}

// ---------------------------------------------------------------------------
extern "C" void kernel_launch(void* const* d_in, const int* in_sizes, int n_in,
                              void* d_out, int out_size, void* d_ws, size_t ws_size,
                              hipStream_t stream) {
    (void)in_sizes; (void)n_in; (void)out_size; (void)ws_size;
    const float* x   = (const float*)d_in[0];
    const int*   y   = (const int*)d_in[1];
    const float* sm  = (const float*)d_in[2];
    const float* Wih = (const float*)d_in[4];
    const float* Whh = (const float*)d_in[5];
    const float* bih = (const float*)d_in[6];
    const float* bhh = (const float*)d_in[7];
    const float* Wfc = (const float*)d_in[8];
    const float* bfc = (const float*)d_in[9];

    char* ws = (char*)d_ws;
    ushort_t* gi      = (ushort_t*)ws;                                  // 100,663,296 B
    ushort_t* hstates = (ushort_t*)(ws + 100663296);                    // 134,217,728 B
    int*      flags   = (int*)(ws + 100663296 + 134217728);             // 4 KB

    hipMemsetAsync(flags, 0, 4096, stream);

    hipLaunchKernelGGL(gi_gemm, dim3((B_*S_/64)*(H3_/64)), dim3(256), 0, stream,
                       x, Wih, bih, gi);

    void* args[] = { (void*)&gi, (void*)&Whh, (void*)&bhh, (void*)&hstates, (void*)&flags };
    hipLaunchCooperativeKernel((void*)rec_kernel, dim3(NC_*CPC_), dim3(256), args, 0, stream);

    hipLaunchKernelGGL(logits_gemm, dim3((B_*T_/64)*(O_/64)), dim3(256), 0, stream,
                       hstates, Wfc, bfc, sm, (float*)d_out);

    float* yout  = (float*)d_out + (size_t)B_*T_*O_;
    float* okout = yout + (size_t)B_*T_;
    hipLaunchKernelGGL(tail_kernel, dim3(B_*T_/256), dim3(256), 0, stream,
                       y, sm, yout, okout);
}